// Round 2
// baseline (3726.225 us; speedup 1.0000x reference)
//
#include <hip/hip_runtime.h>

// Problem constants (B=2, S=2048, D=1024, H=16, Dh=64) — all I/O float32.
#define BB 2
#define SS 2048
#define DD 1024
#define HH 16
#define N3 3072

// ---------------------------------------------------------------------------
// fp32 GEMM: C[M,N] = A[M,K] @ B[K,N]. 64x64 tile / 256 threads, BK=16,
// 4x4 accumulators per thread. M,N,K multiples of 64/16 (no bounds checks).
// ---------------------------------------------------------------------------
__global__ __launch_bounds__(256) void gemm_f32(
    const float* __restrict__ A,
    const float* __restrict__ Bm,
    float* __restrict__ C,
    int K, int N)
{
    __shared__ __align__(16) float As[16][64];   // [k][m]
    __shared__ __align__(16) float Bs[16][64];   // [k][n]
    const int tid = threadIdx.x;
    const int tx = tid & 15;
    const int ty = tid >> 4;
    const int m0 = blockIdx.y * 64;
    const int n0 = blockIdx.x * 64;

    const int arow = tid >> 2, acol = (tid & 3) * 4;   // A tile: 64 x 16
    const int brow = tid >> 4, bcol = (tid & 15) * 4;  // B tile: 16 x 64

    float acc[4][4] = {};

    for (int k0 = 0; k0 < K; k0 += 16) {
        float4 fa = *(const float4*)(A + (size_t)(m0 + arow) * K + k0 + acol);
        float4 fb = *(const float4*)(Bm + (size_t)(k0 + brow) * N + n0 + bcol);
        As[acol + 0][arow] = fa.x;
        As[acol + 1][arow] = fa.y;
        As[acol + 2][arow] = fa.z;
        As[acol + 3][arow] = fa.w;
        *(float4*)&Bs[brow][bcol] = fb;
        __syncthreads();
        #pragma unroll
        for (int kk = 0; kk < 16; ++kk) {
            float4 a4 = *(const float4*)&As[kk][ty * 4];
            float4 b4 = *(const float4*)&Bs[kk][tx * 4];
            float av[4] = {a4.x, a4.y, a4.z, a4.w};
            float bv[4] = {b4.x, b4.y, b4.z, b4.w};
            #pragma unroll
            for (int i = 0; i < 4; ++i)
                #pragma unroll
                for (int j = 0; j < 4; ++j)
                    acc[i][j] += av[i] * bv[j];
        }
        __syncthreads();
    }

    #pragma unroll
    for (int i = 0; i < 4; ++i) {
        float4 o = make_float4(acc[i][0], acc[i][1], acc[i][2], acc[i][3]);
        *(float4*)(C + (size_t)(m0 + ty * 4 + i) * N + n0 + tx * 4) = o;
    }
}

// ---------------------------------------------------------------------------
// RoPE + split qkv[B,S,3*D] -> q,k,v in [B,H,S,Dh] (fp32).
// One thread per (b,s,h,t), t in [0,32): rotation pair (t, t+32).
// ---------------------------------------------------------------------------
__global__ __launch_bounds__(256) void rope_split(
    const float* __restrict__ qkv,
    float* __restrict__ qo,
    float* __restrict__ ko,
    float* __restrict__ vo)
{
    int idx = blockIdx.x * 256 + threadIdx.x;   // B*S*H*32 = 2,097,152
    int t = idx & 31;
    int h = (idx >> 5) & (HH - 1);
    int s = (idx >> 9) & (SS - 1);
    int b = idx >> 20;

    const float* row = qkv + (size_t)(b * SS + s) * N3;
    // inv_freq = 10000^(-t/32); precise powf/sincosf (angle up to 2048 rad).
    float inv_freq = powf(10000.0f, -(float)t * (1.0f / 32.0f));
    float ang = (float)s * inv_freq;
    float sn, c;
    sincosf(ang, &sn, &c);

    float q1 = row[h * 64 + t];
    float q2 = row[h * 64 + t + 32];
    float k1 = row[DD + h * 64 + t];
    float k2 = row[DD + h * 64 + t + 32];

    size_t o = (((size_t)b * HH + h) * SS + s) * 64 + t;
    qo[o]      = q1 * c - q2 * sn;
    qo[o + 32] = q1 * sn + q2 * c;
    ko[o]      = k1 * c - k2 * sn;
    ko[o + 32] = k1 * sn + k2 * c;
    vo[o]      = row[2 * DD + h * 64 + t];
    vo[o + 32] = row[2 * DD + h * 64 + t + 32];
}

// ---------------------------------------------------------------------------
// Attention: one 256-thread block per (b, h, q-row). Two-pass softmax in LDS.
// q,k,v: [B,H,S,Dh] fp32. y out: [B,S,H*Dh] fp32 (GEMM2-ready layout).
// ---------------------------------------------------------------------------
__global__ __launch_bounds__(256) void attn_kernel(
    const float* __restrict__ q,
    const float* __restrict__ k,
    const float* __restrict__ v,
    float* __restrict__ y,
    const int* __restrict__ is_causal,
    const unsigned char* __restrict__ attn_mask)
{
    const int qi = blockIdx.x;
    const int h  = blockIdx.y;
    const int b  = blockIdx.z;
    const int tid = threadIdx.x;

    __shared__ __align__(16) float qs[64];
    __shared__ float sc[SS];
    __shared__ float red[256];
    __shared__ float outred[4][64];

    const size_t bh = (size_t)b * HH + h;
    const float* qrow = q + (bh * SS + qi) * 64;
    if (tid < 64) qs[tid] = qrow[tid];
    __syncthreads();

    const bool causal = (is_causal[0] != 0);
    const int kmax = causal ? (qi + 1) : SS;   // exclusive

    const float* kbase = k + bh * SS * 64;
    for (int kk = tid; kk < SS; kk += 256) {
        float s = -1e38f;
        bool valid = (kk < kmax) && (causal || attn_mask[b * SS + kk]);
        if (valid) {
            const float4* k4 = (const float4*)(kbase + (size_t)kk * 64);
            const float4* q4 = (const float4*)qs;
            float dot = 0.0f;
            #pragma unroll
            for (int d = 0; d < 16; ++d) {
                float4 a = q4[d], bb = k4[d];
                dot += a.x * bb.x + a.y * bb.y + a.z * bb.z + a.w * bb.w;
            }
            s = dot * 0.125f;   // 1/sqrt(64)
        }
        sc[kk] = s;
    }
    __syncthreads();

    // block max
    float m = -1e38f;
    for (int kk = tid; kk < SS; kk += 256) m = fmaxf(m, sc[kk]);
    red[tid] = m;
    __syncthreads();
    #pragma unroll
    for (int off = 128; off > 0; off >>= 1) {
        if (tid < off) red[tid] = fmaxf(red[tid], red[tid + off]);
        __syncthreads();
    }
    m = red[0];
    __syncthreads();

    // exp + block sum
    float lsum = 0.0f;
    for (int kk = tid; kk < SS; kk += 256) {
        float s = sc[kk];
        float p = (s > -1e37f) ? __expf(s - m) : 0.0f;
        sc[kk] = p;
        lsum += p;
    }
    red[tid] = lsum;
    __syncthreads();
    #pragma unroll
    for (int off = 128; off > 0; off >>= 1) {
        if (tid < off) red[tid] += red[tid + off];
        __syncthreads();
    }
    const float linv = 1.0f / red[0];
    __syncthreads();

    // PV: 4 groups of 64 threads; group g handles k = g, g+4, ...
    const int d = tid & 63;
    const int g = tid >> 6;
    const float* vbase = v + bh * SS * 64;
    float acc = 0.0f;
    for (int kk = g; kk < kmax; kk += 4) {
        acc += sc[kk] * vbase[(size_t)kk * 64 + d];
    }
    outred[g][d] = acc;
    __syncthreads();
    if (tid < 64) {
        float o = (outred[0][tid] + outred[1][tid] + outred[2][tid] + outred[3][tid]) * linv;
        y[((size_t)b * SS + qi) * DD + h * 64 + tid] = o;
    }
}

// ---------------------------------------------------------------------------
// Inputs: x[2,2048,1024] f32, qkv_w[1024,3072] f32, out_w[1024,1024] f32,
// attn_mask[2,2048] bool, is_causal int. Output: [2,2048,1024] f32.
// Workspace (fp32): qkv_raw 50.3MB + q/k/v 3x16.8MB = 100.7MB; y aliases
// the dead qkv_raw region after rope_split.
// ---------------------------------------------------------------------------
extern "C" void kernel_launch(void* const* d_in, const int* in_sizes, int n_in,
                              void* d_out, int out_size, void* d_ws, size_t ws_size,
                              hipStream_t stream) {
    const float* x      = (const float*)d_in[0];
    const float* qkv_w  = (const float*)d_in[1];
    const float* out_w  = (const float*)d_in[2];
    const unsigned char* mask = (const unsigned char*)d_in[3];
    const int*   is_c   = (const int*)d_in[4];
    float* out = (float*)d_out;

    float* qkv_raw = (float*)d_ws;                       // [4096, 3072]
    float* qb = qkv_raw + (size_t)4096 * N3;             // [B,H,S,Dh]
    float* kb = qb + (size_t)BB * HH * SS * 64;
    float* vb = kb + (size_t)BB * HH * SS * 64;
    float* yb = qkv_raw;                                 // alias: qkv dead after rope

    // GEMM1: qkv = x @ qkv_w   (M=4096, K=1024, N=3072)
    gemm_f32<<<dim3(N3 / 64, 4096 / 64), 256, 0, stream>>>(x, qkv_w, qkv_raw, DD, N3);

    // RoPE + split into q,k,v [B,H,S,Dh]
    rope_split<<<(BB * SS * HH * 32) / 256, 256, 0, stream>>>(qkv_raw, qb, kb, vb);

    // Attention -> y [B,S,D]
    attn_kernel<<<dim3(SS, HH, BB), 256, 0, stream>>>(qb, kb, vb, yb, is_c, mask);

    // GEMM2: out = y @ out_w   (M=4096, K=1024, N=1024)
    gemm_f32<<<dim3(DD / 64, 4096 / 64), 256, 0, stream>>>(yb, out_w, out, DD, DD);
}

// Round 3
// 693.702 us; speedup vs baseline: 5.3715x; 5.3715x over previous
//
#include <hip/hip_runtime.h>

// Problem constants (B=2, S=2048, D=1024, H=16, Dh=64) — I/O float32.
#define BB 2
#define SS 2048
#define DD 1024
#define HH 16
#define N3 3072

typedef __attribute__((ext_vector_type(8))) short bf16x8;   // 8 bf16 in 4 VGPRs
typedef __attribute__((ext_vector_type(4))) float f32x4;

__device__ __forceinline__ unsigned short f2b(float f) {
    unsigned int x = __float_as_uint(f);
    x += 0x7fffu + ((x >> 16) & 1u);   // RNE
    return (unsigned short)(x >> 16);
}

// ---------------------------------------------------------------------------
// fp32 GEMM: C[M,N] = A[M,K] @ B[K,N]. 64x64 tile / 256 threads, BK=16.
// ---------------------------------------------------------------------------
__global__ __launch_bounds__(256) void gemm_f32(
    const float* __restrict__ A,
    const float* __restrict__ Bm,
    float* __restrict__ C,
    int K, int N)
{
    __shared__ __align__(16) float As[16][64];   // [k][m]
    __shared__ __align__(16) float Bs[16][64];   // [k][n]
    const int tid = threadIdx.x;
    const int tx = tid & 15;
    const int ty = tid >> 4;
    const int m0 = blockIdx.y * 64;
    const int n0 = blockIdx.x * 64;

    const int arow = tid >> 2, acol = (tid & 3) * 4;
    const int brow = tid >> 4, bcol = (tid & 15) * 4;

    float acc[4][4] = {};

    for (int k0 = 0; k0 < K; k0 += 16) {
        float4 fa = *(const float4*)(A + (size_t)(m0 + arow) * K + k0 + acol);
        float4 fb = *(const float4*)(Bm + (size_t)(k0 + brow) * N + n0 + bcol);
        As[acol + 0][arow] = fa.x;
        As[acol + 1][arow] = fa.y;
        As[acol + 2][arow] = fa.z;
        As[acol + 3][arow] = fa.w;
        *(float4*)&Bs[brow][bcol] = fb;
        __syncthreads();
        #pragma unroll
        for (int kk = 0; kk < 16; ++kk) {
            float4 a4 = *(const float4*)&As[kk][ty * 4];
            float4 b4 = *(const float4*)&Bs[kk][tx * 4];
            float av[4] = {a4.x, a4.y, a4.z, a4.w};
            float bv[4] = {b4.x, b4.y, b4.z, b4.w};
            #pragma unroll
            for (int i = 0; i < 4; ++i)
                #pragma unroll
                for (int j = 0; j < 4; ++j)
                    acc[i][j] += av[i] * bv[j];
        }
        __syncthreads();
    }

    #pragma unroll
    for (int i = 0; i < 4; ++i) {
        float4 o = make_float4(acc[i][0], acc[i][1], acc[i][2], acc[i][3]);
        *(float4*)(C + (size_t)(m0 + ty * 4 + i) * N + n0 + tx * 4) = o;
    }
}

// ---------------------------------------------------------------------------
// RoPE + split qkv[B,S,3*D] (fp32) -> q,k,v in [B,H,S,Dh] as BF16.
// One thread per (b,s,h,t), t in [0,32): rotation pair (t, t+32).
// ---------------------------------------------------------------------------
__global__ __launch_bounds__(256) void rope_split(
    const float* __restrict__ qkv,
    unsigned short* __restrict__ qo,
    unsigned short* __restrict__ ko,
    unsigned short* __restrict__ vo)
{
    int idx = blockIdx.x * 256 + threadIdx.x;   // B*S*H*32
    int t = idx & 31;
    int h = (idx >> 5) & (HH - 1);
    int s = (idx >> 9) & (SS - 1);
    int b = idx >> 20;

    const float* row = qkv + (size_t)(b * SS + s) * N3;
    float inv_freq = powf(10000.0f, -(float)t * (1.0f / 32.0f));
    float ang = (float)s * inv_freq;
    float sn, c;
    sincosf(ang, &sn, &c);

    float q1 = row[h * 64 + t];
    float q2 = row[h * 64 + t + 32];
    float k1 = row[DD + h * 64 + t];
    float k2 = row[DD + h * 64 + t + 32];

    size_t o = (((size_t)b * HH + h) * SS + s) * 64 + t;
    qo[o]      = f2b(q1 * c - q2 * sn);
    qo[o + 32] = f2b(q1 * sn + q2 * c);
    ko[o]      = f2b(k1 * c - k2 * sn);
    ko[o + 32] = f2b(k1 * sn + k2 * c);
    vo[o]      = f2b(row[2 * DD + h * 64 + t]);
    vo[o + 32] = f2b(row[2 * DD + h * 64 + t + 32]);
}

// ---------------------------------------------------------------------------
// Flash attention, MFMA 16x16x32 bf16.
// Block = 256 thr = 4 waves; q-tile = 64 rows (16/wave); K/V tiles = 64 keys
// staged in LDS (V transposed). Online softmax in C-layout registers
// (col=lane&15, row=quad*4+reg); P converted C-layout -> A-layout via LDS.
// q,k,v: [B,H,S,64] bf16.  y out: [B,S,H*64] fp32 (GEMM2-ready).
// ---------------------------------------------------------------------------
#define LPAD 8
__global__ __launch_bounds__(256) void flash_attn(
    const unsigned short* __restrict__ q,
    const unsigned short* __restrict__ k,
    const unsigned short* __restrict__ v,
    float* __restrict__ y,
    const int* __restrict__ is_causal,
    const unsigned char* __restrict__ attn_mask)
{
    __shared__ unsigned short Kl[64][64 + LPAD];      // [key][d]
    __shared__ unsigned short Vt[64][64 + LPAD];      // [d][key]  (transposed)
    __shared__ unsigned short Pl[4][16][64 + LPAD];   // per wave [qrow][key]

    const int qt  = blockIdx.x;
    const int h   = blockIdx.y;
    const int b   = blockIdx.z;
    const int tid = threadIdx.x;
    const int wave = tid >> 6;
    const int lane = tid & 63;
    const int quad = lane >> 4;
    const int l16  = lane & 15;

    const size_t bh = (size_t)b * HH + h;
    const int q0 = qt * 64;
    const bool causal = (is_causal[0] != 0);
    const int ntiles = causal ? (qt + 1) : (SS / 64);

    // Q A-fragments: A[m=lane&15][k=quad*8+j]; two K-chunks (d 0..31, 32..63)
    const unsigned short* qrow = q + (bh * SS + q0 + wave * 16 + l16) * 64;
    const bf16x8 qf0 = *(const bf16x8*)(qrow + quad * 8);
    const bf16x8 qf1 = *(const bf16x8*)(qrow + 32 + quad * 8);

    f32x4 O[4];
    #pragma unroll
    for (int st = 0; st < 4; ++st) O[st] = (f32x4){0.f, 0.f, 0.f, 0.f};
    float m_run[4] = {-1e30f, -1e30f, -1e30f, -1e30f};
    float l_run[4] = {0.f, 0.f, 0.f, 0.f};

    const int qg = q0 + wave * 16 + quad * 4;   // +r = this lane's q rows

    // staging coords: thread t handles row tid>>2, 16 elems at (tid&3)*16
    const int srow = tid >> 2;
    const int scol = (tid & 3) * 16;

    for (int kt = 0; kt < ntiles; ++kt) {
        // ---- stage K (row-major) and V (transposed) tiles, fp-free bf16 copy
        {
            const unsigned short* kg = k + (bh * SS + kt * 64 + srow) * 64 + scol;
            const unsigned short* vg = v + (bh * SS + kt * 64 + srow) * 64 + scol;
            uint4 ka = *(const uint4*)kg;
            uint4 kb2 = *(const uint4*)(kg + 8);
            *(uint4*)&Kl[srow][scol]     = ka;
            *(uint4*)&Kl[srow][scol + 8] = kb2;
            unsigned short vv[16];
            *(uint4*)&vv[0] = *(const uint4*)vg;
            *(uint4*)&vv[8] = *(const uint4*)(vg + 8);
            #pragma unroll
            for (int j = 0; j < 16; ++j) Vt[scol + j][srow] = vv[j];
        }
        __syncthreads();

        // ---- S = Q @ K^T  (16 q-rows x 64 keys, 4 N-subtiles)
        f32x4 Sf[4];
        #pragma unroll
        for (int st = 0; st < 4; ++st) {
            bf16x8 kb0 = *(const bf16x8*)&Kl[st * 16 + l16][quad * 8];
            bf16x8 kb1 = *(const bf16x8*)&Kl[st * 16 + l16][32 + quad * 8];
            f32x4 s = (f32x4){0.f, 0.f, 0.f, 0.f};
            s = __builtin_amdgcn_mfma_f32_16x16x32_bf16(qf0, kb0, s, 0, 0, 0);
            s = __builtin_amdgcn_mfma_f32_16x16x32_bf16(qf1, kb1, s, 0, 0, 0);
            Sf[st] = s;
        }

        // ---- scale + mask (finite -1e30 so all-masked rows match reference)
        #pragma unroll
        for (int st = 0; st < 4; ++st) {
            const int keyg = kt * 64 + st * 16 + l16;
            const bool kvalid = causal ? true : (attn_mask[b * SS + keyg] != 0);
            #pragma unroll
            for (int r = 0; r < 4; ++r) {
                float s = Sf[st][r] * 0.125f;   // 1/sqrt(64)
                bool ok = causal ? (keyg <= qg + r) : kvalid;
                Sf[st][r] = ok ? s : -1e30f;
            }
        }

        // ---- online softmax (row = quad*4+r; 16 cols spread over 16 lanes)
        float mnew[4], alpha[4];
        #pragma unroll
        for (int r = 0; r < 4; ++r) {
            float mx = fmaxf(fmaxf(Sf[0][r], Sf[1][r]), fmaxf(Sf[2][r], Sf[3][r]));
            #pragma unroll
            for (int msk = 1; msk <= 8; msk <<= 1) mx = fmaxf(mx, __shfl_xor(mx, msk));
            mnew[r] = fmaxf(m_run[r], mx);
            alpha[r] = __expf(m_run[r] - mnew[r]);
            m_run[r] = mnew[r];
        }
        float lad[4] = {0.f, 0.f, 0.f, 0.f};
        #pragma unroll
        for (int st = 0; st < 4; ++st)
            #pragma unroll
            for (int r = 0; r < 4; ++r) {
                float p = __expf(Sf[st][r] - mnew[r]);
                Sf[st][r] = p;
                lad[r] += p;
            }
        #pragma unroll
        for (int r = 0; r < 4; ++r) {
            float s = lad[r];
            #pragma unroll
            for (int msk = 1; msk <= 8; msk <<= 1) s += __shfl_xor(s, msk);
            l_run[r] = l_run[r] * alpha[r] + s;
            O[0][r] *= alpha[r];
            O[1][r] *= alpha[r];
            O[2][r] *= alpha[r];
            O[3][r] *= alpha[r];
        }

        // ---- P: C-layout regs -> LDS -> A-layout frags (bf16)
        #pragma unroll
        for (int st = 0; st < 4; ++st)
            #pragma unroll
            for (int r = 0; r < 4; ++r)
                Pl[wave][quad * 4 + r][st * 16 + l16] = f2b(Sf[st][r]);
        __syncthreads();

        bf16x8 pf0 = *(const bf16x8*)&Pl[wave][l16][quad * 8];
        bf16x8 pf1 = *(const bf16x8*)&Pl[wave][l16][32 + quad * 8];

        // ---- O += P @ V   (B-frag: B[k=quad*8+j][n=l16] = Vt[dh][key])
        #pragma unroll
        for (int st = 0; st < 4; ++st) {
            bf16x8 vb0 = *(const bf16x8*)&Vt[st * 16 + l16][quad * 8];
            bf16x8 vb1 = *(const bf16x8*)&Vt[st * 16 + l16][32 + quad * 8];
            O[st] = __builtin_amdgcn_mfma_f32_16x16x32_bf16(pf0, vb0, O[st], 0, 0, 0);
            O[st] = __builtin_amdgcn_mfma_f32_16x16x32_bf16(pf1, vb1, O[st], 0, 0, 0);
        }
        __syncthreads();
    }

    // ---- epilogue: y[b][q][h*64+dh] = O / l
    #pragma unroll
    for (int st = 0; st < 4; ++st) {
        #pragma unroll
        for (int r = 0; r < 4; ++r) {
            float val = O[st][r] / l_run[r];
            y[((size_t)b * SS + q0 + wave * 16 + quad * 4 + r) * DD
              + h * 64 + st * 16 + l16] = val;
        }
    }
}

// ---------------------------------------------------------------------------
// Workspace: qkv_raw fp32 [4096,3072] (50.3MB) + q/k/v bf16 [B,H,S,64]
// (3 x 8.4MB). y fp32 aliases qkv_raw (dead after rope). Total ~75.5MB.
// ---------------------------------------------------------------------------
extern "C" void kernel_launch(void* const* d_in, const int* in_sizes, int n_in,
                              void* d_out, int out_size, void* d_ws, size_t ws_size,
                              hipStream_t stream) {
    const float* x      = (const float*)d_in[0];
    const float* qkv_w  = (const float*)d_in[1];
    const float* out_w  = (const float*)d_in[2];
    const unsigned char* mask = (const unsigned char*)d_in[3];
    const int*   is_c   = (const int*)d_in[4];
    float* out = (float*)d_out;

    float* qkv_raw = (float*)d_ws;                              // [4096,3072] f32
    unsigned short* qb = (unsigned short*)(qkv_raw + (size_t)4096 * N3);
    unsigned short* kb = qb + (size_t)BB * HH * SS * 64;
    unsigned short* vb = kb + (size_t)BB * HH * SS * 64;
    float* yb = qkv_raw;                                        // alias

    // GEMM1: qkv = x @ qkv_w   (M=4096, K=1024, N=3072)
    gemm_f32<<<dim3(N3 / 64, 4096 / 64), 256, 0, stream>>>(x, qkv_w, qkv_raw, DD, N3);

    // RoPE + split into bf16 q,k,v [B,H,S,64]
    rope_split<<<(BB * SS * HH * 32) / 256, 256, 0, stream>>>(qkv_raw, qb, kb, vb);

    // Flash attention -> y [B,S,D] fp32
    flash_attn<<<dim3(SS / 64, HH, BB), 256, 0, stream>>>(qb, kb, vb, yb, is_c, mask);

    // GEMM2: out = y @ out_w   (M=4096, K=1024, N=1024)
    gemm_f32<<<dim3(DD / 64, 4096 / 64), 256, 0, stream>>>(yb, out_w, out, DD, DD);
}

// Round 4
// 304.079 us; speedup vs baseline: 12.2541x; 2.2813x over previous
//
#include <hip/hip_runtime.h>

// Problem constants (B=2, S=2048, D=1024, H=16, Dh=64) — I/O float32.
#define BB 2
#define SS 2048
#define DD 1024
#define HH 16
#define N3 3072

typedef __attribute__((ext_vector_type(8))) short bf16x8;   // 8 bf16 in 4 VGPRs
typedef __attribute__((ext_vector_type(4))) float f32x4;

__device__ __forceinline__ float b2f(unsigned short u) {
    return __uint_as_float(((unsigned int)u) << 16);
}
__device__ __forceinline__ unsigned short f2b(float f) {
    unsigned int x = __float_as_uint(f);
    x += 0x7fffu + ((x >> 16) & 1u);   // RNE
    return (unsigned short)(x >> 16);
}
__device__ __forceinline__ void storeC(float* p, float v) { *p = v; }
__device__ __forceinline__ void storeC(unsigned short* p, float v) { *p = f2b(v); }

// async global->LDS, 16B per lane; LDS dest = wave-uniform base + lane*16.
__device__ __forceinline__ void gload_lds16(const void* g, void* l) {
    __builtin_amdgcn_global_load_lds(
        (__attribute__((address_space(1))) void*)g,
        (__attribute__((address_space(3))) void*)l, 16, 0, 0);
}

// ---------------------------------------------------------------------------
// fp32 -> bf16 elementwise cast (n multiple of 1024).
// ---------------------------------------------------------------------------
__global__ __launch_bounds__(256) void cast_f32_bf16(
    const float* __restrict__ src, unsigned short* __restrict__ dst)
{
    int i = (blockIdx.x * 256 + threadIdx.x) * 4;
    float4 f = *(const float4*)(src + i);
    ushort4 o;
    o.x = f2b(f.x); o.y = f2b(f.y); o.z = f2b(f.z); o.w = f2b(f.w);
    *(ushort4*)(dst + i) = o;
}

// ---------------------------------------------------------------------------
// fp32 [R][C] -> bf16 [C][R] cast + transpose. 64x64 tile / 256 threads.
// ---------------------------------------------------------------------------
__global__ __launch_bounds__(256) void cast_transpose(
    const float* __restrict__ src, unsigned short* __restrict__ dst,
    int R, int C)
{
    __shared__ unsigned short tile[64][66];
    const int t = threadIdx.x;
    const int c0 = blockIdx.x * 64, r0 = blockIdx.y * 64;
    const int lr = t >> 4;          // 0..15
    const int lc = (t & 15) * 4;    // 0..60
    #pragma unroll
    for (int i = 0; i < 4; ++i) {
        float4 f = *(const float4*)(src + (size_t)(r0 + lr + i * 16) * C + c0 + lc);
        tile[lr + i * 16][lc + 0] = f2b(f.x);
        tile[lr + i * 16][lc + 1] = f2b(f.y);
        tile[lr + i * 16][lc + 2] = f2b(f.z);
        tile[lr + i * 16][lc + 3] = f2b(f.w);
    }
    __syncthreads();
    #pragma unroll
    for (int i = 0; i < 4; ++i) {
        const int wr = lr + i * 16;       // local col of src = row of dst
        ushort4 o;
        o.x = tile[lc + 0][wr];
        o.y = tile[lc + 1][wr];
        o.z = tile[lc + 2][wr];
        o.w = tile[lc + 3][wr];
        *(ushort4*)(dst + (size_t)(c0 + wr) * R + r0 + lc) = o;
    }
}

// ---------------------------------------------------------------------------
// bf16 MFMA GEMM (m97 structure): C[M,N] = A[M,K] @ Bt[N,K]^T.
// 128x128 tile, BK=32, 256 thr = 4 waves (2x2), each wave 4x4 16x16x32 tiles.
// Staging via global_load_lds width-16 (unpadded LDS). M,N %128, K %32 == 0.
// ---------------------------------------------------------------------------
template <typename OutT>
__global__ __launch_bounds__(256) void gemm_mfma(
    const unsigned short* __restrict__ A,
    const unsigned short* __restrict__ Bt,
    OutT* __restrict__ C,
    int M, int N, int K)
{
    __shared__ unsigned short Al[128 * 32];   // [m][k] row-major
    __shared__ unsigned short Bl[128 * 32];   // [n][k] row-major
    const int tid  = threadIdx.x;
    const int wave = tid >> 6;
    const int lane = tid & 63;
    const int quad = lane >> 4;
    const int l16  = lane & 15;
    const int m0 = blockIdx.y * 128;
    const int n0 = blockIdx.x * 128;
    const int wm = (wave >> 1) * 64;
    const int wn = (wave & 1) * 64;

    // staging: wave w, issue i covers rows w*32+i*16 .. +15, cols (lane&3)*8
    const int srow = wave * 32 + (lane >> 2);
    const int scol = (lane & 3) * 8;
    const unsigned short* gA = A  + (size_t)(m0 + srow) * K + scol;
    const unsigned short* gB = Bt + (size_t)(n0 + srow) * K + scol;

    f32x4 acc[4][4];
    #pragma unroll
    for (int mi = 0; mi < 4; ++mi)
        #pragma unroll
        for (int ni = 0; ni < 4; ++ni)
            acc[mi][ni] = (f32x4){0.f, 0.f, 0.f, 0.f};

    for (int k0 = 0; k0 < K; k0 += 32) {
        __syncthreads();   // previous iteration's ds_reads complete
        #pragma unroll
        for (int i = 0; i < 2; ++i) {
            gload_lds16(gA + (size_t)i * 16 * K + k0, Al + (wave * 2 + i) * 512);
            gload_lds16(gB + (size_t)i * 16 * K + k0, Bl + (wave * 2 + i) * 512);
        }
        __syncthreads();   // staging drained (vmcnt(0) before barrier)

        bf16x8 af[4], bfr[4];
        #pragma unroll
        for (int mi = 0; mi < 4; ++mi)
            af[mi] = *(const bf16x8*)&Al[(wm + mi * 16 + l16) * 32 + quad * 8];
        #pragma unroll
        for (int ni = 0; ni < 4; ++ni)
            bfr[ni] = *(const bf16x8*)&Bl[(wn + ni * 16 + l16) * 32 + quad * 8];
        #pragma unroll
        for (int mi = 0; mi < 4; ++mi)
            #pragma unroll
            for (int ni = 0; ni < 4; ++ni)
                acc[mi][ni] = __builtin_amdgcn_mfma_f32_16x16x32_bf16(
                    af[mi], bfr[ni], acc[mi][ni], 0, 0, 0);
    }

    // epilogue: C[m=quad*4+r][n=l16] per verified C/D layout
    #pragma unroll
    for (int mi = 0; mi < 4; ++mi) {
        #pragma unroll
        for (int r = 0; r < 4; ++r) {
            const size_t base = (size_t)(m0 + wm + mi * 16 + quad * 4 + r) * N + n0 + wn;
            #pragma unroll
            for (int ni = 0; ni < 4; ++ni)
                storeC(&C[base + ni * 16 + l16], acc[mi][ni][r]);
        }
    }
}

// ---------------------------------------------------------------------------
// RoPE + split qkv[B,S,3*D] (bf16) -> q,k,v in [B,H,S,Dh] bf16.
// ---------------------------------------------------------------------------
__global__ __launch_bounds__(256) void rope_split(
    const unsigned short* __restrict__ qkv,
    unsigned short* __restrict__ qo,
    unsigned short* __restrict__ ko,
    unsigned short* __restrict__ vo)
{
    int idx = blockIdx.x * 256 + threadIdx.x;   // B*S*H*32
    int t = idx & 31;
    int h = (idx >> 5) & (HH - 1);
    int s = (idx >> 9) & (SS - 1);
    int b = idx >> 20;

    const unsigned short* row = qkv + (size_t)(b * SS + s) * N3;
    float inv_freq = powf(10000.0f, -(float)t * (1.0f / 32.0f));
    float ang = (float)s * inv_freq;
    float sn, c;
    sincosf(ang, &sn, &c);

    float q1 = b2f(row[h * 64 + t]);
    float q2 = b2f(row[h * 64 + t + 32]);
    float k1 = b2f(row[DD + h * 64 + t]);
    float k2 = b2f(row[DD + h * 64 + t + 32]);

    size_t o = (((size_t)b * HH + h) * SS + s) * 64 + t;
    qo[o]      = f2b(q1 * c - q2 * sn);
    qo[o + 32] = f2b(q1 * sn + q2 * c);
    ko[o]      = f2b(k1 * c - k2 * sn);
    ko[o + 32] = f2b(k1 * sn + k2 * c);
    vo[o]      = row[2 * DD + h * 64 + t];
    vo[o + 32] = row[2 * DD + h * 64 + t + 32];
}

// ---------------------------------------------------------------------------
// Flash attention, MFMA 16x16x32 bf16 (unchanged structure; y out now bf16).
// ---------------------------------------------------------------------------
#define LPAD 8
__global__ __launch_bounds__(256) void flash_attn(
    const unsigned short* __restrict__ q,
    const unsigned short* __restrict__ k,
    const unsigned short* __restrict__ v,
    unsigned short* __restrict__ y,
    const int* __restrict__ is_causal,
    const unsigned char* __restrict__ attn_mask)
{
    __shared__ unsigned short Kl[64][64 + LPAD];      // [key][d]
    __shared__ unsigned short Vt[64][64 + LPAD];      // [d][key]
    __shared__ unsigned short Pl[4][16][64 + LPAD];   // per wave [qrow][key]

    const int qt  = blockIdx.x;
    const int h   = blockIdx.y;
    const int b   = blockIdx.z;
    const int tid = threadIdx.x;
    const int wave = tid >> 6;
    const int lane = tid & 63;
    const int quad = lane >> 4;
    const int l16  = lane & 15;

    const size_t bh = (size_t)b * HH + h;
    const int q0 = qt * 64;
    const bool causal = (is_causal[0] != 0);
    const int ntiles = causal ? (qt + 1) : (SS / 64);

    const unsigned short* qrow = q + (bh * SS + q0 + wave * 16 + l16) * 64;
    const bf16x8 qf0 = *(const bf16x8*)(qrow + quad * 8);
    const bf16x8 qf1 = *(const bf16x8*)(qrow + 32 + quad * 8);

    f32x4 O[4];
    #pragma unroll
    for (int st = 0; st < 4; ++st) O[st] = (f32x4){0.f, 0.f, 0.f, 0.f};
    float m_run[4] = {-1e30f, -1e30f, -1e30f, -1e30f};
    float l_run[4] = {0.f, 0.f, 0.f, 0.f};

    const int qg = q0 + wave * 16 + quad * 4;

    const int srow = tid >> 2;
    const int scol = (tid & 3) * 16;

    for (int kt = 0; kt < ntiles; ++kt) {
        {
            const unsigned short* kg = k + (bh * SS + kt * 64 + srow) * 64 + scol;
            const unsigned short* vg = v + (bh * SS + kt * 64 + srow) * 64 + scol;
            uint4 ka = *(const uint4*)kg;
            uint4 kb2 = *(const uint4*)(kg + 8);
            *(uint4*)&Kl[srow][scol]     = ka;
            *(uint4*)&Kl[srow][scol + 8] = kb2;
            unsigned short vv[16];
            *(uint4*)&vv[0] = *(const uint4*)vg;
            *(uint4*)&vv[8] = *(const uint4*)(vg + 8);
            #pragma unroll
            for (int j = 0; j < 16; ++j) Vt[scol + j][srow] = vv[j];
        }
        __syncthreads();

        f32x4 Sf[4];
        #pragma unroll
        for (int st = 0; st < 4; ++st) {
            bf16x8 kb0 = *(const bf16x8*)&Kl[st * 16 + l16][quad * 8];
            bf16x8 kb1 = *(const bf16x8*)&Kl[st * 16 + l16][32 + quad * 8];
            f32x4 s = (f32x4){0.f, 0.f, 0.f, 0.f};
            s = __builtin_amdgcn_mfma_f32_16x16x32_bf16(qf0, kb0, s, 0, 0, 0);
            s = __builtin_amdgcn_mfma_f32_16x16x32_bf16(qf1, kb1, s, 0, 0, 0);
            Sf[st] = s;
        }

        #pragma unroll
        for (int st = 0; st < 4; ++st) {
            const int keyg = kt * 64 + st * 16 + l16;
            const bool kvalid = causal ? true : (attn_mask[b * SS + keyg] != 0);
            #pragma unroll
            for (int r = 0; r < 4; ++r) {
                float s = Sf[st][r] * 0.125f;
                bool ok = causal ? (keyg <= qg + r) : kvalid;
                Sf[st][r] = ok ? s : -1e30f;
            }
        }

        float mnew[4], alpha[4];
        #pragma unroll
        for (int r = 0; r < 4; ++r) {
            float mx = fmaxf(fmaxf(Sf[0][r], Sf[1][r]), fmaxf(Sf[2][r], Sf[3][r]));
            #pragma unroll
            for (int msk = 1; msk <= 8; msk <<= 1) mx = fmaxf(mx, __shfl_xor(mx, msk));
            mnew[r] = fmaxf(m_run[r], mx);
            alpha[r] = __expf(m_run[r] - mnew[r]);
            m_run[r] = mnew[r];
        }
        float lad[4] = {0.f, 0.f, 0.f, 0.f};
        #pragma unroll
        for (int st = 0; st < 4; ++st)
            #pragma unroll
            for (int r = 0; r < 4; ++r) {
                float p = __expf(Sf[st][r] - mnew[r]);
                Sf[st][r] = p;
                lad[r] += p;
            }
        #pragma unroll
        for (int r = 0; r < 4; ++r) {
            float s = lad[r];
            #pragma unroll
            for (int msk = 1; msk <= 8; msk <<= 1) s += __shfl_xor(s, msk);
            l_run[r] = l_run[r] * alpha[r] + s;
            O[0][r] *= alpha[r];
            O[1][r] *= alpha[r];
            O[2][r] *= alpha[r];
            O[3][r] *= alpha[r];
        }

        #pragma unroll
        for (int st = 0; st < 4; ++st)
            #pragma unroll
            for (int r = 0; r < 4; ++r)
                Pl[wave][quad * 4 + r][st * 16 + l16] = f2b(Sf[st][r]);
        __syncthreads();

        bf16x8 pf0 = *(const bf16x8*)&Pl[wave][l16][quad * 8];
        bf16x8 pf1 = *(const bf16x8*)&Pl[wave][l16][32 + quad * 8];

        #pragma unroll
        for (int st = 0; st < 4; ++st) {
            bf16x8 vb0 = *(const bf16x8*)&Vt[st * 16 + l16][quad * 8];
            bf16x8 vb1 = *(const bf16x8*)&Vt[st * 16 + l16][32 + quad * 8];
            O[st] = __builtin_amdgcn_mfma_f32_16x16x32_bf16(pf0, vb0, O[st], 0, 0, 0);
            O[st] = __builtin_amdgcn_mfma_f32_16x16x32_bf16(pf1, vb1, O[st], 0, 0, 0);
        }
        __syncthreads();
    }

    #pragma unroll
    for (int st = 0; st < 4; ++st) {
        #pragma unroll
        for (int r = 0; r < 4; ++r) {
            float val = O[st][r] / l_run[r];
            y[((size_t)b * SS + q0 + wave * 16 + quad * 4 + r) * DD
              + h * 64 + st * 16 + l16] = f2b(val);
        }
    }
}

// ---------------------------------------------------------------------------
// Workspace (all bf16): xb 4.19M | w1t 3.15M | w2t 1.05M | qkv 12.6M |
// q/k/v 3x4.19M | yb 4.19M  = 37.7M ushort = 75.5 MB.
// ---------------------------------------------------------------------------
extern "C" void kernel_launch(void* const* d_in, const int* in_sizes, int n_in,
                              void* d_out, int out_size, void* d_ws, size_t ws_size,
                              hipStream_t stream) {
    const float* x      = (const float*)d_in[0];
    const float* qkv_w  = (const float*)d_in[1];
    const float* out_w  = (const float*)d_in[2];
    const unsigned char* mask = (const unsigned char*)d_in[3];
    const int*   is_c   = (const int*)d_in[4];
    float* out = (float*)d_out;

    unsigned short* xb  = (unsigned short*)d_ws;
    unsigned short* w1t = xb  + (size_t)4096 * 1024;   // [3072][1024]
    unsigned short* w2t = w1t + (size_t)3072 * 1024;   // [1024][1024]
    unsigned short* qkv = w2t + (size_t)1024 * 1024;   // [4096][3072]
    unsigned short* qb  = qkv + (size_t)4096 * 3072;   // [B,H,S,64]
    unsigned short* kb  = qb  + (size_t)BB * HH * SS * 64;
    unsigned short* vb  = kb  + (size_t)BB * HH * SS * 64;
    unsigned short* yb  = vb  + (size_t)BB * HH * SS * 64;   // [4096][1024]

    // casts: x -> bf16; weights -> bf16 transposed [N][K]
    cast_f32_bf16<<<(4096 * 1024) / 1024, 256, 0, stream>>>(x, xb);
    cast_transpose<<<dim3(N3 / 64, DD / 64), 256, 0, stream>>>(qkv_w, w1t, DD, N3);
    cast_transpose<<<dim3(DD / 64, DD / 64), 256, 0, stream>>>(out_w, w2t, DD, DD);

    // GEMM1: qkv = x @ qkv_w  (M=4096, N=3072, K=1024), bf16 out
    gemm_mfma<unsigned short><<<dim3(N3 / 128, 4096 / 128), 256, 0, stream>>>(
        xb, w1t, qkv, 4096, N3, DD);

    // RoPE + split into bf16 q,k,v [B,H,S,64]
    rope_split<<<(BB * SS * HH * 32) / 256, 256, 0, stream>>>(qkv, qb, kb, vb);

    // Flash attention -> y [B,S,D] bf16
    flash_attn<<<dim3(SS / 64, HH, BB), 256, 0, stream>>>(qb, kb, vb, yb, is_c, mask);

    // GEMM2: out = y @ out_w  (M=4096, N=1024, K=1024), fp32 out
    gemm_mfma<float><<<dim3(DD / 128, 4096 / 128), 256, 0, stream>>>(
        yb, w2t, out, 4096, DD, DD);
}

// Round 5
// 248.687 us; speedup vs baseline: 14.9836x; 1.2227x over previous
//
#include <hip/hip_runtime.h>

// Problem constants (B=2, S=2048, D=1024, H=16, Dh=64) — I/O float32.
#define BB 2
#define SS 2048
#define DD 1024
#define HH 16
#define N3 3072

typedef __attribute__((ext_vector_type(8))) short bf16x8;   // 8 bf16 in 4 VGPRs
typedef __attribute__((ext_vector_type(4))) float f32x4;

__device__ __forceinline__ float b2f(unsigned short u) {
    return __uint_as_float(((unsigned int)u) << 16);
}
__device__ __forceinline__ unsigned short f2b(float f) {
    unsigned int x = __float_as_uint(f);
    x += 0x7fffu + ((x >> 16) & 1u);   // RNE
    return (unsigned short)(x >> 16);
}
__device__ __forceinline__ void storeC(float* p, float v) { *p = v; }
__device__ __forceinline__ void storeC(unsigned short* p, float v) { *p = f2b(v); }

// async global->LDS, 16B/lane; LDS dest = wave-uniform base + lane*16.
__device__ __forceinline__ void gload_lds16(const void* g, void* l) {
    __builtin_amdgcn_global_load_lds(
        (__attribute__((address_space(1))) void*)g,
        (__attribute__((address_space(3))) void*)l, 16, 0, 0);
}

// ---------------------------------------------------------------------------
// sin/cos table: tab[s][t] = (cos, sin)(s * 10000^(-t/32)), fp32. S*32 entries.
// ---------------------------------------------------------------------------
__global__ __launch_bounds__(256) void sincos_tab(float2* __restrict__ tab) {
    int i = blockIdx.x * 256 + threadIdx.x;   // SS*32
    int t = i & 31;
    int s = i >> 5;
    float inv = powf(10000.0f, -(float)t * (1.0f / 32.0f));
    float sn, c;
    sincosf((float)s * inv, &sn, &c);
    tab[i] = make_float2(c, sn);
}

// ---------------------------------------------------------------------------
// fp32 -> bf16 elementwise cast.
// ---------------------------------------------------------------------------
__global__ __launch_bounds__(256) void cast_f32_bf16(
    const float* __restrict__ src, unsigned short* __restrict__ dst)
{
    int i = (blockIdx.x * 256 + threadIdx.x) * 4;
    float4 f = *(const float4*)(src + i);
    ushort4 o;
    o.x = f2b(f.x); o.y = f2b(f.y); o.z = f2b(f.z); o.w = f2b(f.w);
    *(ushort4*)(dst + i) = o;
}

// ---------------------------------------------------------------------------
// fp32 [R][C] -> bf16 [C][R] cast + transpose. 64x64 tile / 256 threads.
// ---------------------------------------------------------------------------
__global__ __launch_bounds__(256) void cast_transpose(
    const float* __restrict__ src, unsigned short* __restrict__ dst,
    int R, int C)
{
    __shared__ unsigned short tile[64][66];
    const int t = threadIdx.x;
    const int c0 = blockIdx.x * 64, r0 = blockIdx.y * 64;
    const int lr = t >> 4;
    const int lc = (t & 15) * 4;
    #pragma unroll
    for (int i = 0; i < 4; ++i) {
        float4 f = *(const float4*)(src + (size_t)(r0 + lr + i * 16) * C + c0 + lc);
        tile[lr + i * 16][lc + 0] = f2b(f.x);
        tile[lr + i * 16][lc + 1] = f2b(f.y);
        tile[lr + i * 16][lc + 2] = f2b(f.z);
        tile[lr + i * 16][lc + 3] = f2b(f.w);
    }
    __syncthreads();
    #pragma unroll
    for (int i = 0; i < 4; ++i) {
        const int wr = lr + i * 16;
        ushort4 o;
        o.x = tile[lc + 0][wr];
        o.y = tile[lc + 1][wr];
        o.z = tile[lc + 2][wr];
        o.w = tile[lc + 3][wr];
        *(ushort4*)(dst + (size_t)(c0 + wr) * R + r0 + lc) = o;
    }
}

// ---------------------------------------------------------------------------
// bf16 MFMA GEMM (m97 structure): C[M,N] = A[M,K] @ Bt[N,K]^T.
// 128x128 tile, BK=32, 4 waves, each 4x4 16x16x32 tiles.
// ---------------------------------------------------------------------------
template <typename OutT>
__global__ __launch_bounds__(256) void gemm_mfma(
    const unsigned short* __restrict__ A,
    const unsigned short* __restrict__ Bt,
    OutT* __restrict__ C,
    int M, int N, int K)
{
    __shared__ unsigned short Al[128 * 32];
    __shared__ unsigned short Bl[128 * 32];
    const int tid  = threadIdx.x;
    const int wave = tid >> 6;
    const int lane = tid & 63;
    const int quad = lane >> 4;
    const int l16  = lane & 15;
    const int m0 = blockIdx.y * 128;
    const int n0 = blockIdx.x * 128;
    const int wm = (wave >> 1) * 64;
    const int wn = (wave & 1) * 64;

    const int srow = wave * 32 + (lane >> 2);
    const int scol = (lane & 3) * 8;
    const unsigned short* gA = A  + (size_t)(m0 + srow) * K + scol;
    const unsigned short* gB = Bt + (size_t)(n0 + srow) * K + scol;

    f32x4 acc[4][4];
    #pragma unroll
    for (int mi = 0; mi < 4; ++mi)
        #pragma unroll
        for (int ni = 0; ni < 4; ++ni)
            acc[mi][ni] = (f32x4){0.f, 0.f, 0.f, 0.f};

    for (int k0 = 0; k0 < K; k0 += 32) {
        __syncthreads();
        #pragma unroll
        for (int i = 0; i < 2; ++i) {
            gload_lds16(gA + (size_t)i * 16 * K + k0, Al + (wave * 2 + i) * 512);
            gload_lds16(gB + (size_t)i * 16 * K + k0, Bl + (wave * 2 + i) * 512);
        }
        __syncthreads();

        bf16x8 af[4], bfr[4];
        #pragma unroll
        for (int mi = 0; mi < 4; ++mi)
            af[mi] = *(const bf16x8*)&Al[(wm + mi * 16 + l16) * 32 + quad * 8];
        #pragma unroll
        for (int ni = 0; ni < 4; ++ni)
            bfr[ni] = *(const bf16x8*)&Bl[(wn + ni * 16 + l16) * 32 + quad * 8];
        #pragma unroll
        for (int mi = 0; mi < 4; ++mi)
            #pragma unroll
            for (int ni = 0; ni < 4; ++ni)
                acc[mi][ni] = __builtin_amdgcn_mfma_f32_16x16x32_bf16(
                    af[mi], bfr[ni], acc[mi][ni], 0, 0, 0);
    }

    #pragma unroll
    for (int mi = 0; mi < 4; ++mi) {
        #pragma unroll
        for (int r = 0; r < 4; ++r) {
            const size_t base = (size_t)(m0 + wm + mi * 16 + quad * 4 + r) * N + n0 + wn;
            #pragma unroll
            for (int ni = 0; ni < 4; ++ni)
                storeC(&C[base + ni * 16 + l16], acc[mi][ni][r]);
        }
    }
}

// ---------------------------------------------------------------------------
// RoPE + split, v2. Grid (S/64, H, B), block 256.
// qkv[B,S,3D] bf16 -> q,k [B,H,S,64] bf16 (roped), vt [B,H,64,S] bf16 (v^T).
// Thread: s_local = tid>>2 (64 rows), qu = tid&3 (d-chunks of 8, pairs qu*8+j
// with 32+qu*8+j). sin/cos from precomputed fp32 table.
// ---------------------------------------------------------------------------
__global__ __launch_bounds__(256) void rope_split(
    const unsigned short* __restrict__ qkv,
    const float2* __restrict__ tab,
    unsigned short* __restrict__ qo,
    unsigned short* __restrict__ ko,
    unsigned short* __restrict__ vt)
{
    __shared__ unsigned short Vtile[64][72];   // [d][s_local]

    const int s0 = blockIdx.x * 64;
    const int h  = blockIdx.y;
    const int b  = blockIdx.z;
    const int tid = threadIdx.x;
    const int sl = tid >> 2;
    const int qu = tid & 3;
    const size_t bh = (size_t)b * HH + h;

    const unsigned short* row = qkv + (size_t)(b * SS + s0 + sl) * N3 + h * 64;

    uint4 a0 = *(const uint4*)(row + qu * 8);
    uint4 a1 = *(const uint4*)(row + 32 + qu * 8);
    uint4 b0 = *(const uint4*)(row + DD + qu * 8);
    uint4 b1 = *(const uint4*)(row + DD + 32 + qu * 8);
    uint4 c0 = *(const uint4*)(row + 2 * DD + qu * 8);
    uint4 c1 = *(const uint4*)(row + 2 * DD + 32 + qu * 8);

    float2 cs[8];
    {
        const float4* tp = (const float4*)(tab + (size_t)(s0 + sl) * 32 + qu * 8);
        #pragma unroll
        for (int i = 0; i < 4; ++i) {
            float4 f = tp[i];
            cs[2 * i]     = make_float2(f.x, f.y);
            cs[2 * i + 1] = make_float2(f.z, f.w);
        }
    }

    const unsigned short* pa0 = (const unsigned short*)&a0;
    const unsigned short* pa1 = (const unsigned short*)&a1;
    const unsigned short* pb0 = (const unsigned short*)&b0;
    const unsigned short* pb1 = (const unsigned short*)&b1;
    const unsigned short* pc0 = (const unsigned short*)&c0;
    const unsigned short* pc1 = (const unsigned short*)&c1;

    unsigned short oq1[8], oq2[8], ok1[8], ok2[8];
    #pragma unroll
    for (int j = 0; j < 8; ++j) {
        float c = cs[j].x, sn = cs[j].y;
        float q1 = b2f(pa0[j]), q2 = b2f(pa1[j]);
        float k1 = b2f(pb0[j]), k2 = b2f(pb1[j]);
        oq1[j] = f2b(q1 * c - q2 * sn);
        oq2[j] = f2b(q1 * sn + q2 * c);
        ok1[j] = f2b(k1 * c - k2 * sn);
        ok2[j] = f2b(k1 * sn + k2 * c);
        Vtile[qu * 8 + j][sl]      = pc0[j];
        Vtile[32 + qu * 8 + j][sl] = pc1[j];
    }
    const size_t qoff = (bh * SS + s0 + sl) * 64;
    *(uint4*)(qo + qoff + qu * 8)      = *(const uint4*)oq1;
    *(uint4*)(qo + qoff + 32 + qu * 8) = *(const uint4*)oq2;
    *(uint4*)(ko + qoff + qu * 8)      = *(const uint4*)ok1;
    *(uint4*)(ko + qoff + 32 + qu * 8) = *(const uint4*)ok2;

    __syncthreads();

    // v^T writeout: thread -> d-row tid>>2, s-chunk tid&3 (16 s each)
    const int dr = tid >> 2;
    const int ch = tid & 3;
    uint4 t0 = *(const uint4*)&Vtile[dr][ch * 16];
    uint4 t1 = *(const uint4*)&Vtile[dr][ch * 16 + 8];
    unsigned short* vrow = vt + (bh * 64 + dr) * SS + s0 + ch * 16;
    *(uint4*)vrow       = t0;
    *(uint4*)(vrow + 8) = t1;
}

// ---------------------------------------------------------------------------
// Flash attention v2: S^T formulation (q = lane column).
//   S^T = K·Q^T  (A=K-frag, B=Q-frag)  -> softmax state is per-lane scalar
//   O^T = V^T·P^T (A=V^T-frag from vt, B=P^T-frag from per-wave LDS)
// K/V^T tiles staged via global_load_lds (16B, XOR-swizzled chunks).
// q,k: [B,H,S,64] bf16; vt: [B,H,64,S] bf16; y: [B,S,H*64] bf16.
// ---------------------------------------------------------------------------
__global__ __launch_bounds__(256) void flash_attn(
    const unsigned short* __restrict__ q,
    const unsigned short* __restrict__ k,
    const unsigned short* __restrict__ vt,
    unsigned short* __restrict__ y,
    const int* __restrict__ is_causal,
    const unsigned char* __restrict__ attn_mask)
{
    __shared__ unsigned short Kl[64 * 64];      // [key][d], 16B chunks swizzled
    __shared__ unsigned short Vl[64 * 64];      // [d][key], 16B chunks swizzled
    __shared__ unsigned short Pq[4][16 * 80];   // per wave [q][key], padded

    const int qt  = blockIdx.x;
    const int h   = blockIdx.y;
    const int b   = blockIdx.z;
    const int tid = threadIdx.x;
    const int wave = tid >> 6;
    const int lane = tid & 63;
    const int quad = lane >> 4;
    const int l16  = lane & 15;

    const size_t bh = (size_t)b * HH + h;
    const int q0 = qt * 64;
    const bool causal = (is_causal[0] != 0);
    const int ntiles = causal ? (qt + 1) : (SS / 64);

    // Q fragment (B-operand): B[k=d=quad*8+j][n=q=l16]
    const unsigned short* qrow = q + (bh * SS + q0 + wave * 16 + l16) * 64;
    const bf16x8 qf0 = *(const bf16x8*)(qrow + quad * 8);
    const bf16x8 qf1 = *(const bf16x8*)(qrow + 32 + quad * 8);

    const unsigned short* kbase  = k  + bh * SS * 64;   // [key][d]
    const unsigned short* vtbase = vt + bh * 64 * SS;   // [d][s]

    // staging lane mapping: row-in-issue = lane>>3, physical chunk = lane&7
    const int Rl  = lane >> 3;
    const int cph = lane & 7;
    // read-side swizzle: logical chunk quad at row (..+l16) -> physical
    const int csw = quad ^ (l16 & 7);

    f32x4 O[4];
    #pragma unroll
    for (int st = 0; st < 4; ++st) O[st] = (f32x4){0.f, 0.f, 0.f, 0.f};
    float m_run = -1e30f, l_run = 0.f;

    const int qg = q0 + wave * 16 + l16;   // this lane's q row

    for (int kt = 0; kt < ntiles; ++kt) {
        // ---- stage K and V^T tiles (4 global_load_lds per wave)
        #pragma unroll
        for (int i = 0; i < 2; ++i) {
            const int R  = (wave * 2 + i) * 8 + Rl;   // tile row 0..63
            const int cl = cph ^ (R & 7);             // logical chunk to fetch
            gload_lds16(kbase + ((size_t)(kt * 64 + R) * 64 + cl * 8),
                        Kl + (wave * 2 + i) * 512);
            gload_lds16(vtbase + ((size_t)R * SS + kt * 64 + cl * 8),
                        Vl + (wave * 2 + i) * 512);
        }
        __syncthreads();   // vmcnt(0) drain: tiles visible to all waves

        // ---- S^T = K·Q^T : 4 key-subtiles
        f32x4 Sf[4];
        #pragma unroll
        for (int st = 0; st < 4; ++st) {
            const unsigned short* kr = &Kl[(st * 16 + l16) * 64];
            bf16x8 kf0 = *(const bf16x8*)(kr + csw * 8);
            bf16x8 kf1 = *(const bf16x8*)(kr + (csw ^ 4) * 8);
            f32x4 s = (f32x4){0.f, 0.f, 0.f, 0.f};
            s = __builtin_amdgcn_mfma_f32_16x16x32_bf16(kf0, qf0, s, 0, 0, 0);
            s = __builtin_amdgcn_mfma_f32_16x16x32_bf16(kf1, qf1, s, 0, 0, 0);
            Sf[st] = s;
        }

        // ---- scale + mask (reg r = key kt*64+st*16+quad*4+r, col = q)
        if (causal) {
            #pragma unroll
            for (int st = 0; st < 4; ++st) {
                const int kb0 = kt * 64 + st * 16 + quad * 4;
                #pragma unroll
                for (int r = 0; r < 4; ++r)
                    Sf[st][r] = (kb0 + r <= qg) ? Sf[st][r] * 0.125f : -1e30f;
            }
        } else {
            #pragma unroll
            for (int st = 0; st < 4; ++st) {
                uchar4 mv = *(const uchar4*)(attn_mask + b * SS + kt * 64
                                             + st * 16 + quad * 4);
                Sf[st][0] = mv.x ? Sf[st][0] * 0.125f : -1e30f;
                Sf[st][1] = mv.y ? Sf[st][1] * 0.125f : -1e30f;
                Sf[st][2] = mv.z ? Sf[st][2] * 0.125f : -1e30f;
                Sf[st][3] = mv.w ? Sf[st][3] * 0.125f : -1e30f;
            }
        }

        // ---- online softmax: per-lane scalar state (q = l16 column)
        float mx = Sf[0][0];
        #pragma unroll
        for (int st = 0; st < 4; ++st)
            #pragma unroll
            for (int r = 0; r < 4; ++r) mx = fmaxf(mx, Sf[st][r]);
        mx = fmaxf(mx, __shfl_xor(mx, 16));
        mx = fmaxf(mx, __shfl_xor(mx, 32));
        const float mnew = fmaxf(m_run, mx);
        const float alpha = __expf(m_run - mnew);
        m_run = mnew;

        float lsum = 0.f;
        #pragma unroll
        for (int st = 0; st < 4; ++st)
            #pragma unroll
            for (int r = 0; r < 4; ++r) {
                float p = __expf(Sf[st][r] - mnew);
                Sf[st][r] = p;
                lsum += p;
            }
        lsum += __shfl_xor(lsum, 16);
        lsum += __shfl_xor(lsum, 32);
        l_run = l_run * alpha + lsum;

        #pragma unroll
        for (int st = 0; st < 4; ++st)
            #pragma unroll
            for (int r = 0; r < 4; ++r) O[st][r] *= alpha;

        // ---- P^T -> per-wave LDS (4 keys/reg-group pack -> ds_write_b64)
        #pragma unroll
        for (int st = 0; st < 4; ++st) {
            uint2 pk;
            pk.x = (unsigned int)f2b(Sf[st][0]) | ((unsigned int)f2b(Sf[st][1]) << 16);
            pk.y = (unsigned int)f2b(Sf[st][2]) | ((unsigned int)f2b(Sf[st][3]) << 16);
            *(uint2*)&Pq[wave][l16 * 80 + st * 16 + quad * 4] = pk;
        }
        // same-wave LDS: in-order DS pipe, no barrier needed

        bf16x8 pf0 = *(const bf16x8*)&Pq[wave][l16 * 80 + quad * 8];
        bf16x8 pf1 = *(const bf16x8*)&Pq[wave][l16 * 80 + 32 + quad * 8];

        // ---- O^T += V^T·P^T : 4 d-subtiles
        #pragma unroll
        for (int st = 0; st < 4; ++st) {
            const unsigned short* vr = &Vl[(st * 16 + l16) * 64];
            bf16x8 vf0 = *(const bf16x8*)(vr + csw * 8);
            bf16x8 vf1 = *(const bf16x8*)(vr + (csw ^ 4) * 8);
            O[st] = __builtin_amdgcn_mfma_f32_16x16x32_bf16(vf0, pf0, O[st], 0, 0, 0);
            O[st] = __builtin_amdgcn_mfma_f32_16x16x32_bf16(vf1, pf1, O[st], 0, 0, 0);
        }
        __syncthreads();   // all waves done reading Kl/Vl before restage
    }

    // ---- epilogue: lane owns q = qg, d = st*16+quad*4+r  (4x 8B stores)
    const float inv = 1.0f / l_run;
    unsigned short* yrow = y + ((size_t)b * SS + qg) * DD + h * 64;
    #pragma unroll
    for (int st = 0; st < 4; ++st) {
        uint2 o;
        o.x = (unsigned int)f2b(O[st][0] * inv) | ((unsigned int)f2b(O[st][1] * inv) << 16);
        o.y = (unsigned int)f2b(O[st][2] * inv) | ((unsigned int)f2b(O[st][3] * inv) << 16);
        *(uint2*)(yrow + st * 16 + quad * 4) = o;
    }
}

// ---------------------------------------------------------------------------
// Workspace (ushort units unless noted):
//   xb/yb (aliased) 4096*1024 | w1t 3072*1024 | w2t 1024*1024 |
//   qkv 4096*3072 | qb 4.19M | kb 4.19M | vt 4.19M | tab float2[65536]
// Total ~67.6 MB.
// ---------------------------------------------------------------------------
extern "C" void kernel_launch(void* const* d_in, const int* in_sizes, int n_in,
                              void* d_out, int out_size, void* d_ws, size_t ws_size,
                              hipStream_t stream) {
    const float* x      = (const float*)d_in[0];
    const float* qkv_w  = (const float*)d_in[1];
    const float* out_w  = (const float*)d_in[2];
    const unsigned char* mask = (const unsigned char*)d_in[3];
    const int*   is_c   = (const int*)d_in[4];
    float* out = (float*)d_out;

    unsigned short* xb  = (unsigned short*)d_ws;             // aliased with yb
    unsigned short* w1t = xb  + (size_t)4096 * 1024;
    unsigned short* w2t = w1t + (size_t)3072 * 1024;
    unsigned short* qkv = w2t + (size_t)1024 * 1024;
    unsigned short* qb  = qkv + (size_t)4096 * 3072;
    unsigned short* kb  = qb  + (size_t)BB * HH * SS * 64;
    unsigned short* vt  = kb  + (size_t)BB * HH * SS * 64;
    float2* tab = (float2*)(vt + (size_t)BB * HH * SS * 64);
    unsigned short* yb = xb;   // x dead after GEMM1

    sincos_tab<<<(SS * 32) / 256, 256, 0, stream>>>(tab);
    cast_f32_bf16<<<(4096 * 1024) / 1024, 256, 0, stream>>>(x, xb);
    cast_transpose<<<dim3(N3 / 64, DD / 64), 256, 0, stream>>>(qkv_w, w1t, DD, N3);
    cast_transpose<<<dim3(DD / 64, DD / 64), 256, 0, stream>>>(out_w, w2t, DD, DD);

    // GEMM1: qkv = x @ qkv_w  (M=4096, N=3072, K=1024)
    gemm_mfma<unsigned short><<<dim3(N3 / 128, 4096 / 128), 256, 0, stream>>>(
        xb, w1t, qkv, 4096, N3, DD);

    // RoPE + split: q,k [B,H,S,64]; v^T [B,H,64,S]
    rope_split<<<dim3(SS / 64, HH, BB), 256, 0, stream>>>(qkv, tab, qb, kb, vt);

    // Flash attention (S^T form) -> y [B,S,D] bf16
    flash_attn<<<dim3(SS / 64, HH, BB), 256, 0, stream>>>(qb, kb, vt, yb, is_c, mask);

    // GEMM2: out = y @ out_w  (M=4096, N=1024, K=1024), fp32 out
    gemm_mfma<float><<<dim3(DD / 128, 4096 / 128), 256, 0, stream>>>(
        yb, w2t, out, 4096, DD, DD);
}

// Round 6
// 244.209 us; speedup vs baseline: 15.2584x; 1.0183x over previous
//
#include <hip/hip_runtime.h>
#include <hip/hip_bf16.h>

// Problem constants (B=2, S=2048, D=1024, H=16, Dh=64) — I/O float32.
#define BB 2
#define SS 2048
#define DD 1024
#define HH 16
#define N3 3072

typedef __attribute__((ext_vector_type(8))) short bf16x8;   // 8 bf16 in 4 VGPRs
typedef __attribute__((ext_vector_type(4))) float f32x4;

__device__ __forceinline__ float b2f(unsigned short u) {
    return __uint_as_float(((unsigned int)u) << 16);
}
__device__ __forceinline__ unsigned short f2b(float f) {
    unsigned int x = __float_as_uint(f);
    x += 0x7fffu + ((x >> 16) & 1u);   // RNE
    return (unsigned short)(x >> 16);
}
__device__ __forceinline__ unsigned int pack2bf(float a, float b) {
    __hip_bfloat162 h = __float22bfloat162_rn(make_float2(a, b));  // v_cvt_pk_bf16_f32
    return *(unsigned int*)&h;
}
__device__ __forceinline__ void storeC(float* p, float v) { *p = v; }
__device__ __forceinline__ void storeC(unsigned short* p, float v) { *p = f2b(v); }

// async global->LDS, 16B/lane; LDS dest = wave-uniform base + lane*16.
__device__ __forceinline__ void gload_lds16(const void* g, void* l) {
    __builtin_amdgcn_global_load_lds(
        (__attribute__((address_space(1))) void*)g,
        (__attribute__((address_space(3))) void*)l, 16, 0, 0);
}

// ---------------------------------------------------------------------------
// sin/cos table: tab[s][t] = (cos, sin)(s * 10000^(-t/32)), fp32.
// ---------------------------------------------------------------------------
__global__ __launch_bounds__(256) void sincos_tab(float2* __restrict__ tab) {
    int i = blockIdx.x * 256 + threadIdx.x;   // SS*32
    int t = i & 31;
    int s = i >> 5;
    float inv = powf(10000.0f, -(float)t * (1.0f / 32.0f));
    float sn, c;
    sincosf((float)s * inv, &sn, &c);
    tab[i] = make_float2(c, sn);
}

// ---------------------------------------------------------------------------
// fp32 -> bf16 elementwise cast.
// ---------------------------------------------------------------------------
__global__ __launch_bounds__(256) void cast_f32_bf16(
    const float* __restrict__ src, unsigned short* __restrict__ dst)
{
    int i = (blockIdx.x * 256 + threadIdx.x) * 4;
    float4 f = *(const float4*)(src + i);
    uint2 o;
    o.x = pack2bf(f.x, f.y);
    o.y = pack2bf(f.z, f.w);
    *(uint2*)(dst + i) = o;
}

// ---------------------------------------------------------------------------
// fp32 [R][C] -> bf16 [C][R] cast + transpose. 64x64 tile / 256 threads.
// ---------------------------------------------------------------------------
__global__ __launch_bounds__(256) void cast_transpose(
    const float* __restrict__ src, unsigned short* __restrict__ dst,
    int R, int C)
{
    __shared__ unsigned short tile[64][66];
    const int t = threadIdx.x;
    const int c0 = blockIdx.x * 64, r0 = blockIdx.y * 64;
    const int lr = t >> 4;
    const int lc = (t & 15) * 4;
    #pragma unroll
    for (int i = 0; i < 4; ++i) {
        float4 f = *(const float4*)(src + (size_t)(r0 + lr + i * 16) * C + c0 + lc);
        tile[lr + i * 16][lc + 0] = f2b(f.x);
        tile[lr + i * 16][lc + 1] = f2b(f.y);
        tile[lr + i * 16][lc + 2] = f2b(f.z);
        tile[lr + i * 16][lc + 3] = f2b(f.w);
    }
    __syncthreads();
    #pragma unroll
    for (int i = 0; i < 4; ++i) {
        const int wr = lr + i * 16;
        ushort4 o;
        o.x = tile[lc + 0][wr];
        o.y = tile[lc + 1][wr];
        o.z = tile[lc + 2][wr];
        o.w = tile[lc + 3][wr];
        *(ushort4*)(dst + (size_t)(c0 + wr) * R + r0 + lc) = o;
    }
}

// ---------------------------------------------------------------------------
// bf16 MFMA GEMM: C[M,N] = A[M,K] @ Bt[N,K]^T. Tile 128 x TN, BK=32, 4 waves
// (2x2), wave computes 64 x TN/2 via 4 x (TN/32) 16x16x32 MFMA tiles.
// ---------------------------------------------------------------------------
template <typename OutT, int TN>
__global__ __launch_bounds__(256) void gemm_mfma(
    const unsigned short* __restrict__ A,
    const unsigned short* __restrict__ Bt,
    OutT* __restrict__ C,
    int M, int N, int K)
{
    constexpr int NI = TN / 32;   // n-subtiles per wave
    constexpr int NB = TN / 64;   // B staging issues per wave
    __shared__ unsigned short Al[128 * 32];
    __shared__ unsigned short Bl[TN * 32];
    const int tid  = threadIdx.x;
    const int wave = tid >> 6;
    const int lane = tid & 63;
    const int quad = lane >> 4;
    const int l16  = lane & 15;
    const int m0 = blockIdx.y * 128;
    const int n0 = blockIdx.x * TN;
    const int wm = (wave >> 1) * 64;
    const int wn = (wave & 1) * (TN / 2);

    const int srowA = wave * 32 + (lane >> 2);
    const int srowB = wave * (16 * NB) + (lane >> 2);
    const int scol  = (lane & 3) * 8;
    const unsigned short* gA = A  + (size_t)(m0 + srowA) * K + scol;
    const unsigned short* gB = Bt + (size_t)(n0 + srowB) * K + scol;

    f32x4 acc[4][NI];
    #pragma unroll
    for (int mi = 0; mi < 4; ++mi)
        #pragma unroll
        for (int ni = 0; ni < NI; ++ni)
            acc[mi][ni] = (f32x4){0.f, 0.f, 0.f, 0.f};

    for (int k0 = 0; k0 < K; k0 += 32) {
        __syncthreads();
        #pragma unroll
        for (int i = 0; i < 2; ++i)
            gload_lds16(gA + (size_t)i * 16 * K + k0, Al + (wave * 2 + i) * 512);
        #pragma unroll
        for (int i = 0; i < NB; ++i)
            gload_lds16(gB + (size_t)i * 16 * K + k0, Bl + (wave * NB + i) * 512);
        __syncthreads();

        bf16x8 af[4], bfr[NI];
        #pragma unroll
        for (int mi = 0; mi < 4; ++mi)
            af[mi] = *(const bf16x8*)&Al[(wm + mi * 16 + l16) * 32 + quad * 8];
        #pragma unroll
        for (int ni = 0; ni < NI; ++ni)
            bfr[ni] = *(const bf16x8*)&Bl[(wn + ni * 16 + l16) * 32 + quad * 8];
        #pragma unroll
        for (int mi = 0; mi < 4; ++mi)
            #pragma unroll
            for (int ni = 0; ni < NI; ++ni)
                acc[mi][ni] = __builtin_amdgcn_mfma_f32_16x16x32_bf16(
                    af[mi], bfr[ni], acc[mi][ni], 0, 0, 0);
    }

    #pragma unroll
    for (int mi = 0; mi < 4; ++mi) {
        #pragma unroll
        for (int r = 0; r < 4; ++r) {
            const size_t base = (size_t)(m0 + wm + mi * 16 + quad * 4 + r) * N + n0 + wn;
            #pragma unroll
            for (int ni = 0; ni < NI; ++ni)
                storeC(&C[base + ni * 16 + l16], acc[mi][ni][r]);
        }
    }
}

// ---------------------------------------------------------------------------
// RoPE + split. Grid (S/64, H, B), block 256.
// qkv[B,S,3D] bf16 -> q,k [B,H,S,64] bf16 (roped), vt [B,H,64,S] bf16 (v^T).
// ---------------------------------------------------------------------------
__global__ __launch_bounds__(256) void rope_split(
    const unsigned short* __restrict__ qkv,
    const float2* __restrict__ tab,
    unsigned short* __restrict__ qo,
    unsigned short* __restrict__ ko,
    unsigned short* __restrict__ vt)
{
    __shared__ unsigned short Vtile[64][72];   // [d][s_local]

    const int s0 = blockIdx.x * 64;
    const int h  = blockIdx.y;
    const int b  = blockIdx.z;
    const int tid = threadIdx.x;
    const int sl = tid >> 2;
    const int qu = tid & 3;
    const size_t bh = (size_t)b * HH + h;

    const unsigned short* row = qkv + (size_t)(b * SS + s0 + sl) * N3 + h * 64;

    uint4 a0 = *(const uint4*)(row + qu * 8);
    uint4 a1 = *(const uint4*)(row + 32 + qu * 8);
    uint4 b0 = *(const uint4*)(row + DD + qu * 8);
    uint4 b1 = *(const uint4*)(row + DD + 32 + qu * 8);
    uint4 c0 = *(const uint4*)(row + 2 * DD + qu * 8);
    uint4 c1 = *(const uint4*)(row + 2 * DD + 32 + qu * 8);

    float2 cs[8];
    {
        const float4* tp = (const float4*)(tab + (size_t)(s0 + sl) * 32 + qu * 8);
        #pragma unroll
        for (int i = 0; i < 4; ++i) {
            float4 f = tp[i];
            cs[2 * i]     = make_float2(f.x, f.y);
            cs[2 * i + 1] = make_float2(f.z, f.w);
        }
    }

    const unsigned short* pa0 = (const unsigned short*)&a0;
    const unsigned short* pa1 = (const unsigned short*)&a1;
    const unsigned short* pb0 = (const unsigned short*)&b0;
    const unsigned short* pb1 = (const unsigned short*)&b1;
    const unsigned short* pc0 = (const unsigned short*)&c0;
    const unsigned short* pc1 = (const unsigned short*)&c1;

    unsigned short oq1[8], oq2[8], ok1[8], ok2[8];
    #pragma unroll
    for (int j = 0; j < 8; ++j) {
        float c = cs[j].x, sn = cs[j].y;
        float q1 = b2f(pa0[j]), q2 = b2f(pa1[j]);
        float k1 = b2f(pb0[j]), k2 = b2f(pb1[j]);
        oq1[j] = f2b(q1 * c - q2 * sn);
        oq2[j] = f2b(q1 * sn + q2 * c);
        ok1[j] = f2b(k1 * c - k2 * sn);
        ok2[j] = f2b(k1 * sn + k2 * c);
        Vtile[qu * 8 + j][sl]      = pc0[j];
        Vtile[32 + qu * 8 + j][sl] = pc1[j];
    }
    const size_t qoff = (bh * SS + s0 + sl) * 64;
    *(uint4*)(qo + qoff + qu * 8)      = *(const uint4*)oq1;
    *(uint4*)(qo + qoff + 32 + qu * 8) = *(const uint4*)oq2;
    *(uint4*)(ko + qoff + qu * 8)      = *(const uint4*)ok1;
    *(uint4*)(ko + qoff + 32 + qu * 8) = *(const uint4*)ok2;

    __syncthreads();

    const int dr = tid >> 2;
    const int ch = tid & 3;
    uint4 t0 = *(const uint4*)&Vtile[dr][ch * 16];
    uint4 t1 = *(const uint4*)&Vtile[dr][ch * 16 + 8];
    unsigned short* vrow = vt + (bh * 64 + dr) * SS + s0 + ch * 16;
    *(uint4*)vrow       = t0;
    *(uint4*)(vrow + 8) = t1;
}

// ---------------------------------------------------------------------------
// Flash attention v3: S^T formulation, log2-domain softmax.
//  - off-diagonal causal tiles: NO per-element mask (only kt==qt masks)
//  - scores scaled once by 0.125*log2e, exp2f native
//  - heavy-first block order (LPT) for the causal triangle
// q,k: [B,H,S,64] bf16; vt: [B,H,64,S] bf16; y: [B,S,H*64] bf16.
// ---------------------------------------------------------------------------
__global__ __launch_bounds__(256) void flash_attn(
    const unsigned short* __restrict__ q,
    const unsigned short* __restrict__ k,
    const unsigned short* __restrict__ vt,
    unsigned short* __restrict__ y,
    const int* __restrict__ is_causal,
    const unsigned char* __restrict__ attn_mask)
{
    __shared__ unsigned short Kl[64 * 64];      // [key][d], 16B chunks swizzled
    __shared__ unsigned short Vl[64 * 64];      // [d][key], 16B chunks swizzled
    __shared__ unsigned short Pq[4][16 * 72];   // per wave [q][key], stride 72

    const int qt  = (int)gridDim.x - 1 - (int)blockIdx.x;   // heavy-first
    const int h   = blockIdx.y;
    const int b   = blockIdx.z;
    const int tid = threadIdx.x;
    const int wave = tid >> 6;
    const int lane = tid & 63;
    const int quad = lane >> 4;
    const int l16  = lane & 15;

    const size_t bh = (size_t)b * HH + h;
    const int q0 = qt * 64;
    const bool causal = (is_causal[0] != 0);
    const int ntiles = causal ? (qt + 1) : (SS / 64);

    const float SC = 0.18033688011112042f;   // 0.125 * log2(e)

    // Q fragment (B-operand): B[k=d=quad*8+j][n=q=l16]
    const unsigned short* qrow = q + (bh * SS + q0 + wave * 16 + l16) * 64;
    const bf16x8 qf0 = *(const bf16x8*)(qrow + quad * 8);
    const bf16x8 qf1 = *(const bf16x8*)(qrow + 32 + quad * 8);

    const unsigned short* kbase  = k  + bh * SS * 64;   // [key][d]
    const unsigned short* vtbase = vt + bh * 64 * SS;   // [d][s]

    const int Rl  = lane >> 3;
    const int cph = lane & 7;
    const int csw = quad ^ (l16 & 7);

    f32x4 O[4];
    #pragma unroll
    for (int st = 0; st < 4; ++st) O[st] = (f32x4){0.f, 0.f, 0.f, 0.f};
    float m_run = -1e30f, l_run = 0.f;

    const int qg = q0 + wave * 16 + l16;   // this lane's q row

    for (int kt = 0; kt < ntiles; ++kt) {
        // ---- stage K and V^T tiles (4 global_load_lds per wave)
        #pragma unroll
        for (int i = 0; i < 2; ++i) {
            const int R  = (wave * 2 + i) * 8 + Rl;
            const int cl = cph ^ (R & 7);
            gload_lds16(kbase + ((size_t)(kt * 64 + R) * 64 + cl * 8),
                        Kl + (wave * 2 + i) * 512);
            gload_lds16(vtbase + ((size_t)R * SS + kt * 64 + cl * 8),
                        Vl + (wave * 2 + i) * 512);
        }
        __syncthreads();

        // ---- S^T = K·Q^T : 4 key-subtiles; scale into log2 domain
        f32x4 Sf[4];
        #pragma unroll
        for (int st = 0; st < 4; ++st) {
            const unsigned short* kr = &Kl[(st * 16 + l16) * 64];
            bf16x8 kf0 = *(const bf16x8*)(kr + csw * 8);
            bf16x8 kf1 = *(const bf16x8*)(kr + (csw ^ 4) * 8);
            f32x4 s = (f32x4){0.f, 0.f, 0.f, 0.f};
            s = __builtin_amdgcn_mfma_f32_16x16x32_bf16(kf0, qf0, s, 0, 0, 0);
            s = __builtin_amdgcn_mfma_f32_16x16x32_bf16(kf1, qf1, s, 0, 0, 0);
            #pragma unroll
            for (int r = 0; r < 4; ++r) s[r] *= SC;
            Sf[st] = s;
        }

        // ---- mask: only the diagonal tile (causal) or attn_mask (non-causal)
        if (causal) {
            if (kt == qt) {
                #pragma unroll
                for (int st = 0; st < 4; ++st) {
                    const int kb0 = kt * 64 + st * 16 + quad * 4;
                    #pragma unroll
                    for (int r = 0; r < 4; ++r)
                        if (kb0 + r > qg) Sf[st][r] = -1e30f;
                }
            }
        } else {
            #pragma unroll
            for (int st = 0; st < 4; ++st) {
                uchar4 mv = *(const uchar4*)(attn_mask + b * SS + kt * 64
                                             + st * 16 + quad * 4);
                if (!mv.x) Sf[st][0] = -1e30f;
                if (!mv.y) Sf[st][1] = -1e30f;
                if (!mv.z) Sf[st][2] = -1e30f;
                if (!mv.w) Sf[st][3] = -1e30f;
            }
        }

        // ---- online softmax, log2 domain, per-lane scalar state
        float mx = Sf[0][0];
        #pragma unroll
        for (int st = 0; st < 4; ++st)
            #pragma unroll
            for (int r = 0; r < 4; ++r) mx = fmaxf(mx, Sf[st][r]);
        mx = fmaxf(mx, __shfl_xor(mx, 16));
        mx = fmaxf(mx, __shfl_xor(mx, 32));
        const float mnew = fmaxf(m_run, mx);
        const float alpha = exp2f(m_run - mnew);
        m_run = mnew;

        float lsum = 0.f;
        #pragma unroll
        for (int st = 0; st < 4; ++st)
            #pragma unroll
            for (int r = 0; r < 4; ++r) {
                float p = exp2f(Sf[st][r] - mnew);
                Sf[st][r] = p;
                lsum += p;
            }
        lsum += __shfl_xor(lsum, 16);
        lsum += __shfl_xor(lsum, 32);
        l_run = l_run * alpha + lsum;

        #pragma unroll
        for (int st = 0; st < 4; ++st)
            #pragma unroll
            for (int r = 0; r < 4; ++r) O[st][r] *= alpha;

        // ---- P^T -> per-wave LDS (packed bf16 pairs, ds_write_b64)
        #pragma unroll
        for (int st = 0; st < 4; ++st) {
            uint2 pk;
            pk.x = pack2bf(Sf[st][0], Sf[st][1]);
            pk.y = pack2bf(Sf[st][2], Sf[st][3]);
            *(uint2*)&Pq[wave][l16 * 72 + st * 16 + quad * 4] = pk;
        }
        // same-wave LDS round-trip: in-order DS pipe, no barrier needed

        bf16x8 pf0 = *(const bf16x8*)&Pq[wave][l16 * 72 + quad * 8];
        bf16x8 pf1 = *(const bf16x8*)&Pq[wave][l16 * 72 + 32 + quad * 8];

        // ---- O^T += V^T·P^T : 4 d-subtiles
        #pragma unroll
        for (int st = 0; st < 4; ++st) {
            const unsigned short* vr = &Vl[(st * 16 + l16) * 64];
            bf16x8 vf0 = *(const bf16x8*)(vr + csw * 8);
            bf16x8 vf1 = *(const bf16x8*)(vr + (csw ^ 4) * 8);
            O[st] = __builtin_amdgcn_mfma_f32_16x16x32_bf16(vf0, pf0, O[st], 0, 0, 0);
            O[st] = __builtin_amdgcn_mfma_f32_16x16x32_bf16(vf1, pf1, O[st], 0, 0, 0);
        }
        __syncthreads();   // all waves done reading Kl/Vl before restage
    }

    // ---- epilogue: lane owns q = qg, d = st*16+quad*4+r
    const float inv = 1.0f / l_run;
    unsigned short* yrow = y + ((size_t)b * SS + qg) * DD + h * 64;
    #pragma unroll
    for (int st = 0; st < 4; ++st) {
        uint2 o;
        o.x = pack2bf(O[st][0] * inv, O[st][1] * inv);
        o.y = pack2bf(O[st][2] * inv, O[st][3] * inv);
        *(uint2*)(yrow + st * 16 + quad * 4) = o;
    }
}

// ---------------------------------------------------------------------------
// Workspace: xb/yb (aliased) | w1t | w2t | qkv | qb | kb | vt | tab. ~67.6 MB.
// ---------------------------------------------------------------------------
extern "C" void kernel_launch(void* const* d_in, const int* in_sizes, int n_in,
                              void* d_out, int out_size, void* d_ws, size_t ws_size,
                              hipStream_t stream) {
    const float* x      = (const float*)d_in[0];
    const float* qkv_w  = (const float*)d_in[1];
    const float* out_w  = (const float*)d_in[2];
    const unsigned char* mask = (const unsigned char*)d_in[3];
    const int*   is_c   = (const int*)d_in[4];
    float* out = (float*)d_out;

    unsigned short* xb  = (unsigned short*)d_ws;             // aliased with yb
    unsigned short* w1t = xb  + (size_t)4096 * 1024;
    unsigned short* w2t = w1t + (size_t)3072 * 1024;
    unsigned short* qkv = w2t + (size_t)1024 * 1024;
    unsigned short* qb  = qkv + (size_t)4096 * 3072;
    unsigned short* kb  = qb  + (size_t)BB * HH * SS * 64;
    unsigned short* vt  = kb  + (size_t)BB * HH * SS * 64;
    float2* tab = (float2*)(vt + (size_t)BB * HH * SS * 64);
    unsigned short* yb = xb;   // x dead after GEMM1

    sincos_tab<<<(SS * 32) / 256, 256, 0, stream>>>(tab);
    cast_f32_bf16<<<(4096 * 1024) / 1024, 256, 0, stream>>>(x, xb);
    cast_transpose<<<dim3(N3 / 64, DD / 64), 256, 0, stream>>>(qkv_w, w1t, DD, N3);
    cast_transpose<<<dim3(DD / 64, DD / 64), 256, 0, stream>>>(out_w, w2t, DD, DD);

    // GEMM1: qkv = x @ qkv_w  (M=4096, N=3072, K=1024), tile 128x128
    gemm_mfma<unsigned short, 128><<<dim3(N3 / 128, 4096 / 128), 256, 0, stream>>>(
        xb, w1t, qkv, 4096, N3, DD);

    // RoPE + split: q,k [B,H,S,64]; v^T [B,H,64,S]
    rope_split<<<dim3(SS / 64, HH, BB), 256, 0, stream>>>(qkv, tab, qb, kb, vt);

    // Flash attention (S^T form, log2 softmax) -> y [B,S,D] bf16
    flash_attn<<<dim3(SS / 64, HH, BB), 256, 0, stream>>>(qb, kb, vt, yb, is_c, mask);

    // GEMM2: out = y @ out_w  (M=4096, N=1024, K=1024), tile 128x64 -> 512 blocks
    gemm_mfma<float, 64><<<dim3(DD / 64, 4096 / 128), 256, 0, stream>>>(
        yb, w2t, out, 4096, DD, DD);
}